// Round 4
// baseline (15479.588 us; speedup 1.0000x reference)
//
#include <hip/hip_runtime.h>

// GRU scan, 2 layers, B=64 T=4096 D=H=128 — layer-specialized waves,
// swapped MFMA operands (weights = A-operand, activations = B-operand),
// ONE barrier per step.
//
// 4 persistent WGs x 16 batch rows x 512 threads (8 waves).
// Waves 0-3 = layer 0, waves 4-7 = layer 1 (skew 1 step: L1 sigma = t-1).
// MFMA m=unit, n=batch: D[unit][batch]; lane holds 4 consecutive units of
// batch col lc -> h commit is ONE ds_write_b64 per tile (no b16 scatter).
// Weight A-frags stationary in VGPR/AGPR: 48 frags (one layer, 2 unit-tiles).
// B-frags (activations) read from LDS frag-linear blocks (lane*16 b128,
// conflict-free), shared by both tiles: 8 reads/wave/step.
//
// Region(t), single barrier at end:
//   L0: input=X[t&1], h=H0[(t-1)&1], gates->h0(t)->H0[t&1]
//   L1: input=H0[(t-1)&1], h=H1[(t-2)&1], gates->h1(t-1)->H1[(t-1)&1]
//   all: global-prefetch x(t+1) early, stage into X[(t+1)&1] late.
// Hazards: every (write,read) pair is separated by exactly one barrier;
// every (read, overwrite) pair likewise (double buffers, skew 1).

#define Tlen 4096
#define Hd   128
#define Bsz  64

typedef __attribute__((ext_vector_type(8))) short short8;     // 8 bf16
typedef __attribute__((ext_vector_type(4))) short short4v;    // 4 bf16
typedef __attribute__((ext_vector_type(4))) float float4v;
typedef __attribute__((ext_vector_type(2))) unsigned int uint2v;

#define MFMA16(a, b, c) __builtin_amdgcn_mfma_f32_16x16x32_bf16((a), (b), (c), 0, 0, 0)

static __device__ __forceinline__ float fast_exp2(float x) {
#if __has_builtin(__builtin_amdgcn_exp2f)
  return __builtin_amdgcn_exp2f(x);
#else
  return exp2f(x);
#endif
}
static __device__ __forceinline__ float fast_rcp(float x) {
  return __builtin_amdgcn_rcpf(x);
}
static __device__ __forceinline__ short f2bf(float f) {  // RTNE fp32->bf16
  unsigned u = __builtin_bit_cast(unsigned, f);
  u = (u + 0x7FFFu + ((u >> 16) & 1u)) >> 16;
  return (short)u;
}
static __device__ __forceinline__ unsigned pk2bf(float a, float b) {  // lo=a hi=b
#if __has_builtin(__builtin_amdgcn_cvt_pk_bf16_f32)
  auto v = __builtin_amdgcn_cvt_pk_bf16_f32(a, b);
  return __builtin_bit_cast(unsigned, v);
#else
  return (unsigned)(unsigned short)f2bf(a) | ((unsigned)(unsigned short)f2bf(b) << 16);
#endif
}
static __device__ __forceinline__ short8 loadw8(const float* __restrict__ p) {
  short8 r;
  #pragma unroll
  for (int j = 0; j < 8; ++j) r[j] = f2bf(p[j]);
  return r;
}

// LDS blocks (short indices). Block = 2048 shorts = [batch 16][k 128] in
// B-frag-linear layout: addr(b,k) = (k>>5)*512 + ((k>>3)&3)*128 + b*8 + (k&7).
// Reader lane l, kstep s: b128 at s*512 + l*8.
#define XB   0
#define H0B  4096
#define H1B  8192
#define BLK  2048

__global__ __launch_bounds__(512, 2) void gru_scan(
    const float* __restrict__ x,
    const float* __restrict__ Wih0, const float* __restrict__ Whh0,
    const float* __restrict__ bih0, const float* __restrict__ bhh0,
    const float* __restrict__ Wih1, const float* __restrict__ Whh1,
    const float* __restrict__ bih1, const float* __restrict__ bhh1,
    float* __restrict__ out) {
  __shared__ alignas(16) short Abuf[12288];  // 24 KB

  const int tid   = threadIdx.x;
  const int wave  = tid >> 6;
  const int lane  = tid & 63;
  const int lc    = lane & 15;     // A: m(unit) | B: n(batch) | C: col(batch)
  const int quad  = lane >> 4;
  const int q8    = quad * 8;
  const int lane8 = lane * 8;
  const int bbase = blockIdx.x * 16;

  const int wgrp = wave >> 2;      // 0 = layer0, 1 = layer1
  const int w4   = wave & 3;       // unit-block [32*w4, 32*w4+32)

  const float* Wi = wgrp ? Wih1 : Wih0;
  const float* Wh = wgrp ? Whh1 : Whh0;
  const float* bi = wgrp ? bih1 : bih0;
  const float* bh = wgrp ? bhh1 : bhh0;

  // ---- stationary weight A-frags: lane holds W[U0+lc][32s+q8+j] ----------
  short8 wxr[2][4], wxz[2][4], wxn[2][4];   // input-side (Wih)
  short8 whr[2][4], whz[2][4], whn[2][4];   // hidden-side (Whh)
  float kr[2][4], kz[2][4], ki[2][4], kh[2][4];
  const float nL  = -1.44269504088896f;     // -log2(e)
  const float n2L = -2.88539008177793f;     // -2*log2(e)
  #pragma unroll
  for (int T = 0; T < 2; ++T) {
    const int U0 = 32 * w4 + 16 * T;
    #pragma unroll
    for (int s = 0; s < 4; ++s) {
      const int k = 32 * s + q8;
      wxr[T][s] = loadw8(Wi + (U0 + lc) * Hd + k);
      wxz[T][s] = loadw8(Wi + (128 + U0 + lc) * Hd + k);
      wxn[T][s] = loadw8(Wi + (256 + U0 + lc) * Hd + k);
      whr[T][s] = loadw8(Wh + (U0 + lc) * Hd + k);
      whz[T][s] = loadw8(Wh + (128 + U0 + lc) * Hd + k);
      whn[T][s] = loadw8(Wh + (256 + U0 + lc) * Hd + k);
    }
    #pragma unroll
    for (int i = 0; i < 4; ++i) {
      const int U = U0 + quad * 4 + i;   // this lane's unit for acc reg i
      kr[T][i] = nL  * (bi[U] + bh[U]);
      kz[T][i] = nL  * (bi[128 + U] + bh[128 + U]);
      ki[T][i] = n2L * bi[256 + U];
      kh[T][i] = n2L * bh[256 + U];
    }
  }

  const int ib0 = wgrp ? H0B : XB;     // input-frag block base
  const int hb0 = wgrp ? H1B : H0B;    // h-frag block base (read & write)

  // h commit offsets: units U0+quad*4+[0..3], batch lc -> 4 contiguous shorts
  int wroff[2];
  #pragma unroll
  for (int T = 0; T < 2; ++T)
    wroff[T] = w4 * 512 + (2 * T + (quad >> 1)) * 128 + lc * 8 + 4 * (quad & 1);

  // x staging: thread -> (batch row, k0..k0+3), 4 contiguous shorts
  const int xrow  = tid >> 5;
  const int xk0   = 4 * (tid & 31);
  const int xwoff = (xk0 >> 5) * 512 + ((xk0 >> 3) & 3) * 128 + xrow * 8 + (xk0 & 7);
  const float* xg = x + (size_t)(bbase + xrow) * (Tlen * Hd) + xk0;

  // ---- prologue: zero H0/H1 (both bufs), stage x(0) into X[0] ------------
  {
    int* zb = (int*)Abuf;   // dwords [2048, 6144) == shorts [4096, 12288)
    #pragma unroll
    for (int i = 0; i < 8; ++i) zb[2048 + tid + 512 * i] = 0;
    const float4v v0 = *(const float4v*)(xg);
    uint2v pp = {pk2bf(v0[0], v0[1]), pk2bf(v0[2], v0[3])};
    *(short4v*)&Abuf[XB + xwoff] = __builtin_bit_cast(short4v, pp);
  }
  __syncthreads();

  const float4v Z4 = {0.f, 0.f, 0.f, 0.f};
  float4v hp[2] = {Z4, Z4};            // fp32 h (this wave's units x batch lc)

  // ---- main loop: Tlen+1 regions (1-step drain for layer 1) --------------
  #pragma unroll 2
  for (int t = 0; t <= Tlen; ++t) {
    const int ibase = ib0 + ((t + wgrp) & 1) * BLK;
    const int hbase = hb0 + ((t + 1 + wgrp) & 1) * BLK;
    const int wbase = hb0 + ((t + wgrp) & 1) * BLK;

    // global prefetch x(t+1) (consumed next region)
    const int tn = (t + 1 < Tlen) ? (t + 1) : (Tlen - 1);
    const float4v xv = *(const float4v*)(xg + (size_t)tn * Hd);

    // B-frags (shared across both unit-tiles)
    short8 bfi[4], bfh[4];
    #pragma unroll
    for (int s = 0; s < 4; ++s)
      bfi[s] = *(const short8*)&Abuf[ibase + s * 512 + lane8];
    #pragma unroll
    for (int s = 0; s < 4; ++s)
      bfh[s] = *(const short8*)&Abuf[hbase + s * 512 + lane8];

    // ---- MFMAs: 24 per tile (weights = A, acts = B, zero-C hoisted) ----
    float4v aR[2], aZ[2], aIN[2], aHN[2];
    #pragma unroll
    for (int T = 0; T < 2; ++T) {
      aR[T]  = MFMA16(wxr[T][0], bfi[0], Z4);
      aZ[T]  = MFMA16(wxz[T][0], bfi[0], Z4);
      aIN[T] = MFMA16(wxn[T][0], bfi[0], Z4);
      aHN[T] = MFMA16(whn[T][0], bfh[0], Z4);
      #pragma unroll
      for (int s = 1; s < 4; ++s) {
        aR[T]  = MFMA16(wxr[T][s], bfi[s], aR[T]);
        aZ[T]  = MFMA16(wxz[T][s], bfi[s], aZ[T]);
        aIN[T] = MFMA16(wxn[T][s], bfi[s], aIN[T]);
        aHN[T] = MFMA16(whn[T][s], bfh[s], aHN[T]);
      }
      #pragma unroll
      for (int s = 0; s < 4; ++s) {
        aR[T] = MFMA16(whr[T][s], bfh[s], aR[T]);
        aZ[T] = MFMA16(whz[T][s], bfh[s], aZ[T]);
      }
    }

    // ---- gates (always computed; commit guarded) ----
    const bool gv = wgrp ? (t >= 1) : (t < Tlen);
    #pragma unroll
    for (int T = 0; T < 2; ++T) {
      float hn[4];
      #pragma unroll
      for (int i = 0; i < 4; ++i) {
        const float er = fast_exp2(fmaf(aR[T][i], nL, kr[T][i]));
        const float rr = fast_rcp(1.0f + er);
        const float ez = fast_exp2(fmaf(aZ[T][i], nL, kz[T][i]));
        const float zz = fast_rcp(1.0f + ez);
        float vv = fmaf(rr, fmaf(aHN[T][i], n2L, kh[T][i]),
                        fmaf(aIN[T][i], n2L, ki[T][i]));
        vv = fminf(vv, 126.0f);
        const float e2 = fast_exp2(vv);
        const float nn = (1.0f - e2) * fast_rcp(1.0f + e2);
        hn[i] = fmaf(zz, hp[T][i] - nn, nn);
      }
      if (gv) {
        #pragma unroll
        for (int i = 0; i < 4; ++i) hp[T][i] = hn[i];
        uint2v pp = {pk2bf(hn[0], hn[1]), pk2bf(hn[2], hn[3])};
        *(short4v*)&Abuf[wbase + wroff[T]] = __builtin_bit_cast(short4v, pp);
      }
    }

    // ---- stage x(t+1) into X[(t+1)&1] (old content last read region t-1) --
    {
      uint2v pp = {pk2bf(xv[0], xv[1]), pk2bf(xv[2], xv[3])};
      *(short4v*)&Abuf[XB + ((t + 1) & 1) * BLK + xwoff] =
          __builtin_bit_cast(short4v, pp);
    }
    __syncthreads();
  }

  // ---- output: L0 waves hold h0(T-1), L1 waves hold h1(T-1) --------------
  #pragma unroll
  for (int T = 0; T < 2; ++T) {
    #pragma unroll
    for (int i = 0; i < 4; ++i) {
      const int u = 32 * w4 + 16 * T + quad * 4 + i;
      const int b = bbase + lc;
      out[wgrp * (Bsz * Hd) + b * Hd + u] = hp[T][i];
    }
  }
}

extern "C" void kernel_launch(void* const* d_in, const int* in_sizes, int n_in,
                              void* d_out, int out_size, void* d_ws, size_t ws_size,
                              hipStream_t stream) {
  (void)in_sizes; (void)n_in; (void)out_size; (void)d_ws; (void)ws_size;
  gru_scan<<<4, 512, 0, stream>>>(
      (const float*)d_in[0],
      (const float*)d_in[1], (const float*)d_in[2],
      (const float*)d_in[3], (const float*)d_in[4],
      (const float*)d_in[5], (const float*)d_in[6],
      (const float*)d_in[7], (const float*)d_in[8],
      (float*)d_out);
}

// Round 5
// 7391.355 us; speedup vs baseline: 2.0943x; 2.0943x over previous
//
#include <hip/hip_runtime.h>

// GRU scan, 2 layers, B=64 T=4096 D=H=128 — v5.
// Key change vs R3: layer-0's input projection G = bf16(x @ Wih0^T) is
// precomputed for ALL t by a full-chip GEMM into d_ws (201 MB), removing
// 24 of 48 MFMAs/wave/step from the serial loop. Serial kernel keeps R3's
// empirically-good two-phase skeleton (gates interleaved between MFMA
// blocks, 2 barriers/step).
//
// Serial kernel: 4 WGs x 512 thr; wave w owns unit-tile w (16 units) of
// BOTH layers. Per region t:
//   P1: read h0(t-1) frags; gates h1(t-2) [accs from P2(t-1)] + commit;
//       MFMA Whh0*h0(t-1) [12] + Wih1*h0(t-1) [12, SAME B-frags].
//   P2: read h1(t-2) frags; gates h0(t) [P1 accs + G(t) regs] + commit;
//       MFMA Whh1*h1(t-2) [12]; refill G(t+2) prefetch regs.
// Hazards: H0/H1 double-buffered; every write->read and read->overwrite
// pair separated by >=1 barrier (verified per-buffer).
// Fallback (ws too small): R3 kernel verbatim.

#define Tlen 4096
#define Hd   128
#define Bsz  64

typedef __attribute__((ext_vector_type(8))) short short8;     // 8 bf16
typedef __attribute__((ext_vector_type(4))) short short4v;    // 4 bf16
typedef __attribute__((ext_vector_type(4))) float float4v;
typedef __attribute__((ext_vector_type(2))) unsigned int uint2v;
typedef __attribute__((ext_vector_type(4))) unsigned int uint4v;

#define MFMA16(a, b, c) __builtin_amdgcn_mfma_f32_16x16x32_bf16((a), (b), (c), 0, 0, 0)

static __device__ __forceinline__ float fast_exp2(float x) {
#if __has_builtin(__builtin_amdgcn_exp2f)
  return __builtin_amdgcn_exp2f(x);
#else
  return exp2f(x);
#endif
}
static __device__ __forceinline__ float fast_rcp(float x) {
  return __builtin_amdgcn_rcpf(x);
}
static __device__ __forceinline__ short f2bf(float f) {  // RTNE fp32->bf16
  unsigned u = __builtin_bit_cast(unsigned, f);
  u = (u + 0x7FFFu + ((u >> 16) & 1u)) >> 16;
  return (short)u;
}
static __device__ __forceinline__ unsigned pk2bf(float a, float b) {  // lo=a hi=b
#if __has_builtin(__builtin_amdgcn_cvt_pk_bf16_f32)
  auto v = __builtin_amdgcn_cvt_pk_bf16_f32(a, b);
  return __builtin_bit_cast(unsigned, v);
#else
  return (unsigned)(unsigned short)f2bf(a) | ((unsigned)(unsigned short)f2bf(b) << 16);
#endif
}
static __device__ __forceinline__ short8 loadw8(const float* __restrict__ p) {
  short8 r;
  #pragma unroll
  for (int j = 0; j < 8; ++j) r[j] = f2bf(p[j]);
  return r;
}
static __device__ __forceinline__ float bfsel(uint2v d, int i) {
  const unsigned u = (i & 1) ? (d[i >> 1] & 0xFFFF0000u) : (d[i >> 1] << 16);
  return __builtin_bit_cast(float, u);
}

// ============================ producer =====================================
// G layout (shorts): idx = ((((bb*4096 + t)*8 + w)*3 + g)*64 + lane)*4 + i
// value = (Wih0 @ x_t^T)[gate g, unit 16w+quad*4+i, batch bb*16+lc], bf16.
__global__ __launch_bounds__(512, 2) void gru_pre(
    const float* __restrict__ x, const float* __restrict__ Wih0,
    short* __restrict__ G) {
  const int tid  = threadIdx.x;
  const int w    = tid >> 6;
  const int lane = tid & 63;
  const int lc   = lane & 15;
  const int quad = lane >> 4;
  const int q8   = quad * 8;
  const int bb   = blockIdx.x & 3;
  const int c    = blockIdx.x >> 2;     // t-chunk of 128

  short8 fr[4], fz[4], fn[4];
  #pragma unroll
  for (int s = 0; s < 4; ++s) {
    const int k = 32 * s + q8;
    fr[s] = loadw8(Wih0 + (16 * w + lc) * Hd + k);
    fz[s] = loadw8(Wih0 + (128 + 16 * w + lc) * Hd + k);
    fn[s] = loadw8(Wih0 + (256 + 16 * w + lc) * Hd + k);
  }
  const float* xrow = x + (size_t)(bb * 16 + lc) * (Tlen * Hd);
  const float4v Z4 = {0.f, 0.f, 0.f, 0.f};

  for (int tt = 0; tt < 128; ++tt) {
    const int t = c * 128 + tt;
    short8 bx[4];
    #pragma unroll
    for (int s = 0; s < 4; ++s) {
      const float* p = xrow + (size_t)t * Hd + 32 * s + q8;
      const float4v lo = *(const float4v*)p;
      const float4v hi = *(const float4v*)(p + 4);
      uint4v u = {pk2bf(lo[0], lo[1]), pk2bf(lo[2], lo[3]),
                  pk2bf(hi[0], hi[1]), pk2bf(hi[2], hi[3])};
      bx[s] = __builtin_bit_cast(short8, u);
    }
    float4v gr = Z4, gz = Z4, gn = Z4;
    #pragma unroll
    for (int s = 0; s < 4; ++s) {
      gr = MFMA16(fr[s], bx[s], gr);
      gz = MFMA16(fz[s], bx[s], gz);
      gn = MFMA16(fn[s], bx[s], gn);
    }
    const size_t base = ((((size_t)bb * Tlen + t) * 8 + w) * 3) * 256;
    uint2v pr = {pk2bf(gr[0], gr[1]), pk2bf(gr[2], gr[3])};
    uint2v pz = {pk2bf(gz[0], gz[1]), pk2bf(gz[2], gz[3])};
    uint2v pn = {pk2bf(gn[0], gn[1]), pk2bf(gn[2], gn[3])};
    *(uint2v*)&G[base + 0 * 256 + lane * 4] = pr;
    *(uint2v*)&G[base + 1 * 256 + lane * 4] = pz;
    *(uint2v*)&G[base + 2 * 256 + lane * 4] = pn;
  }
}

// ============================ serial consumer ==============================
// LDS: H0[2], H1[2] frag-linear blocks of 2048 shorts (16 KB total).
// addr(b,k) = (k>>5)*512 + ((k>>3)&3)*128 + b*8 + (k&7); reader lane l,
// kstep s: b128 at s*512 + l*8 (conflict-free m97 pattern).
#define CH0  0
#define CH1  4096
#define BLK  2048

__global__ __launch_bounds__(512, 2) void gru_scan(
    const float* __restrict__ Whh0,
    const float* __restrict__ bih0, const float* __restrict__ bhh0,
    const float* __restrict__ Wih1, const float* __restrict__ Whh1,
    const float* __restrict__ bih1, const float* __restrict__ bhh1,
    const short* __restrict__ G, float* __restrict__ out) {
  __shared__ alignas(16) short Abuf[8192];

  const int tid   = threadIdx.x;
  const int w     = tid >> 6;      // unit-tile (both layers)
  const int lane  = tid & 63;
  const int lc    = lane & 15;
  const int quad  = lane >> 4;
  const int q8    = quad * 8;
  const int lane8 = lane * 8;
  const int bbase = blockIdx.x * 16;

  // stationary weight A-frags: Whh0 / Wih1 / Whh1 for unit-tile w
  short8 whr0[4], whz0[4], whn0[4];
  short8 wxr1[4], wxz1[4], wxn1[4];
  short8 whr1[4], whz1[4], whn1[4];
  #pragma unroll
  for (int s = 0; s < 4; ++s) {
    const int k = 32 * s + q8;
    const int ur = 16 * w + lc, uz = 128 + 16 * w + lc, un = 256 + 16 * w + lc;
    whr0[s] = loadw8(Whh0 + ur * Hd + k);
    whz0[s] = loadw8(Whh0 + uz * Hd + k);
    whn0[s] = loadw8(Whh0 + un * Hd + k);
    wxr1[s] = loadw8(Wih1 + ur * Hd + k);
    wxz1[s] = loadw8(Wih1 + uz * Hd + k);
    wxn1[s] = loadw8(Wih1 + un * Hd + k);
    whr1[s] = loadw8(Whh1 + ur * Hd + k);
    whz1[s] = loadw8(Whh1 + uz * Hd + k);
    whn1[s] = loadw8(Whh1 + un * Hd + k);
  }

  const float nL  = -1.44269504088896f;   // -log2(e)
  const float n2L = -2.88539008177793f;   // -2*log2(e)
  float kr0[4], kz0[4], ki0[4], kh0[4], kr1[4], kz1[4], ki1[4], kh1[4];
  #pragma unroll
  for (int i = 0; i < 4; ++i) {
    const int u = 16 * w + quad * 4 + i;
    kr0[i] = nL  * (bih0[u] + bhh0[u]);
    kz0[i] = nL  * (bih0[128 + u] + bhh0[128 + u]);
    ki0[i] = n2L * bih0[256 + u];
    kh0[i] = n2L * bhh0[256 + u];
    kr1[i] = nL  * (bih1[u] + bhh1[u]);
    kz1[i] = nL  * (bih1[128 + u] + bhh1[128 + u]);
    ki1[i] = n2L * bih1[256 + u];
    kh1[i] = n2L * bhh1[256 + u];
  }

  // h commit offset (frag layout) for unit-tile w, this lane's 4 units
  const int wroff = (w >> 1) * 512 + ((2 * w + (quad >> 1)) & 3) * 128 +
                    lc * 8 + 4 * (quad & 1);

  // G addressing: bytes; per-region stride 8*3*512 = 12288 B
  const char* Gp = (const char*)G;
  const size_t gbase = (((size_t)blockIdx.x * Tlen * 8 + w) * 3) * 512 + lane * 8;

  // prologue: zero LDS, prefetch G(0), G(1)
  {
    int* zb = (int*)Abuf;
    #pragma unroll
    for (int i = 0; i < 8; ++i) zb[tid + 512 * i] = 0;
  }
  uint2v G2[2][3];
  #pragma unroll
  for (int g = 0; g < 3; ++g) {
    G2[0][g] = *(const uint2v*)(Gp + gbase + g * 512);
    G2[1][g] = *(const uint2v*)(Gp + gbase + 12288 + g * 512);
  }
  __syncthreads();

  const float4v Z4 = {0.f, 0.f, 0.f, 0.f};
  float4v aR = Z4, aZ = Z4, aHN = Z4;            // L0 accs (hh parts)
  float4v cR = Z4, cZ = Z4, cIN = Z4, cHN = Z4;  // L1 accs
  float h0p[4] = {0.f, 0.f, 0.f, 0.f};
  float h1p[4] = {0.f, 0.f, 0.f, 0.f};

  #pragma unroll 2
  for (int t = 0; t < Tlen + 2; ++t) {
    const int p = t & 1;

    // ---------------- P1 ----------------
    short8 hf[4];   // h0(t-1) frags
    #pragma unroll
    for (int s = 0; s < 4; ++s)
      hf[s] = *(const short8*)&Abuf[CH0 + (p ^ 1) * BLK + s * 512 + lane8];

    if (t >= 2) {   // gates h1(t-2) from L1 accs; commit -> H1[t&1]
      float hn[4];
      #pragma unroll
      for (int i = 0; i < 4; ++i) {
        const float er = fast_exp2(fmaf(cR[i], nL, kr1[i]));
        const float rr = fast_rcp(1.0f + er);
        const float ez = fast_exp2(fmaf(cZ[i], nL, kz1[i]));
        const float zz = fast_rcp(1.0f + ez);
        float vv = fmaf(rr, fmaf(cHN[i], n2L, kh1[i]),
                        fmaf(cIN[i], n2L, ki1[i]));
        vv = fminf(vv, 126.0f);
        const float e2 = fast_exp2(vv);
        const float nn = (1.0f - e2) * fast_rcp(1.0f + e2);
        hn[i] = fmaf(zz, h1p[i] - nn, nn);
        h1p[i] = hn[i];
      }
      uint2v pp = {pk2bf(hn[0], hn[1]), pk2bf(hn[2], hn[3])};
      *(short4v*)&Abuf[CH1 + p * BLK + wroff] = __builtin_bit_cast(short4v, pp);
    }

    // MFMAs: L0hh(t) + L1ih(t-1), both on h0(t-1) B-frags
    aR  = MFMA16(whr0[0], hf[0], Z4);
    aZ  = MFMA16(whz0[0], hf[0], Z4);
    aHN = MFMA16(whn0[0], hf[0], Z4);
    cR  = MFMA16(wxr1[0], hf[0], Z4);
    cZ  = MFMA16(wxz1[0], hf[0], Z4);
    cIN = MFMA16(wxn1[0], hf[0], Z4);
    #pragma unroll
    for (int s = 1; s < 4; ++s) {
      aR  = MFMA16(whr0[s], hf[s], aR);
      aZ  = MFMA16(whz0[s], hf[s], aZ);
      aHN = MFMA16(whn0[s], hf[s], aHN);
      cR  = MFMA16(wxr1[s], hf[s], cR);
      cZ  = MFMA16(wxz1[s], hf[s], cZ);
      cIN = MFMA16(wxn1[s], hf[s], cIN);
    }
    __syncthreads();

    // ---------------- P2 ----------------
    short8 gf[4];   // h1(t-2) frags (committed in P1 this region)
    #pragma unroll
    for (int s = 0; s < 4; ++s)
      gf[s] = *(const short8*)&Abuf[CH1 + p * BLK + s * 512 + lane8];

    if (t < Tlen) {  // gates h0(t) = f(G(t), L0 accs); commit -> H0[t&1]
      float hn[4];
      #pragma unroll
      for (int i = 0; i < 4; ++i) {
        const float gr = bfsel(G2[p][0], i);
        const float gz = bfsel(G2[p][1], i);
        const float gn = bfsel(G2[p][2], i);
        const float er = fast_exp2(fmaf(aR[i] + gr, nL, kr0[i]));
        const float rr = fast_rcp(1.0f + er);
        const float ez = fast_exp2(fmaf(aZ[i] + gz, nL, kz0[i]));
        const float zz = fast_rcp(1.0f + ez);
        float vv = fmaf(rr, fmaf(aHN[i], n2L, kh0[i]),
                        fmaf(gn, n2L, ki0[i]));
        vv = fminf(vv, 126.0f);
        const float e2 = fast_exp2(vv);
        const float nn = (1.0f - e2) * fast_rcp(1.0f + e2);
        hn[i] = fmaf(zz, h0p[i] - nn, nn);
        h0p[i] = hn[i];
      }
      uint2v pp = {pk2bf(hn[0], hn[1]), pk2bf(hn[2], hn[3])};
      *(short4v*)&Abuf[CH0 + p * BLK + wroff] = __builtin_bit_cast(short4v, pp);
    }

    // L1hh(t-1) on h1(t-2) frags
    cHN = MFMA16(whn1[0], gf[0], Z4);
    cR  = MFMA16(whr1[0], gf[0], cR);
    cZ  = MFMA16(whz1[0], gf[0], cZ);
    #pragma unroll
    for (int s = 1; s < 4; ++s) {
      cHN = MFMA16(whn1[s], gf[s], cHN);
      cR  = MFMA16(whr1[s], gf[s], cR);
      cZ  = MFMA16(whz1[s], gf[s], cZ);
    }

    // refill G slot p with G(t+2) (consumed above; reused in P2(t+2))
    {
      const int tg = (t + 2 < Tlen) ? (t + 2) : (Tlen - 1);
      const size_t go = gbase + (size_t)tg * 12288;
      #pragma unroll
      for (int g = 0; g < 3; ++g)
        G2[p][g] = *(const uint2v*)(Gp + go + g * 512);
    }
    __syncthreads();
  }

  // ---- output ------------------------------------------------------------
  #pragma unroll
  for (int i = 0; i < 4; ++i) {
    const int u = 16 * w + quad * 4 + i;
    const int b = bbase + lc;
    out[b * Hd + u]            = h0p[i];
    out[Bsz * Hd + b * Hd + u] = h1p[i];
  }
}

// ============================ fallback (R3 kernel) =========================
#define FXB   0
#define FH0B  4096
#define FH1B  8192
#define FBLK  2048

__global__ __launch_bounds__(512, 2) void gru_scan_fb(
    const float* __restrict__ x,
    const float* __restrict__ Wih0, const float* __restrict__ Whh0,
    const float* __restrict__ bih0, const float* __restrict__ bhh0,
    const float* __restrict__ Wih1, const float* __restrict__ Whh1,
    const float* __restrict__ bih1, const float* __restrict__ bhh1,
    float* __restrict__ out) {
  __shared__ alignas(16) short Abuf[12288];

  const int tid   = threadIdx.x;
  const int wave  = tid >> 6;
  const int lane  = tid & 63;
  const int lc    = lane & 15;
  const int quad  = lane >> 4;
  const int q8    = quad * 8;
  const int lane8 = lane * 8;
  const int bbase = blockIdx.x * 16;
  const int wgrp = wave >> 2;
  const int w4   = wave & 3;

  const float* Wi = wgrp ? Wih1 : Wih0;
  const float* Wh = wgrp ? Whh1 : Whh0;
  const float* bi = wgrp ? bih1 : bih0;
  const float* bh = wgrp ? bhh1 : bhh0;

  short8 fxr[2][4], fxz[2][4], fxn[2][4];
  short8 fhr[2][4], fhz[2][4], fhn[2][4];
  float kr[2], kz[2], ki[2], kh[2];
  const float nL  = -1.44269504088896f;
  const float n2L = -2.88539008177793f;
  #pragma unroll
  for (int Gg = 0; Gg < 2; ++Gg) {
    const int c = 32 * w4 + 16 * Gg + lc;
    #pragma unroll
    for (int s = 0; s < 4; ++s) {
      const int k = 32 * s + q8;
      fxr[Gg][s] = loadw8(Wi + (c) * Hd + k);
      fxz[Gg][s] = loadw8(Wi + (128 + c) * Hd + k);
      fxn[Gg][s] = loadw8(Wi + (256 + c) * Hd + k);
      fhr[Gg][s] = loadw8(Wh + (c) * Hd + k);
      fhz[Gg][s] = loadw8(Wh + (128 + c) * Hd + k);
      fhn[Gg][s] = loadw8(Wh + (256 + c) * Hd + k);
    }
    kr[Gg] = nL  * (bi[c] + bh[c]);
    kz[Gg] = nL  * (bi[128 + c] + bh[128 + c]);
    ki[Gg] = n2L * bi[256 + c];
    kh[Gg] = n2L * bh[256 + c];
  }
  const int hsel = wgrp ? FH1B : FH0B;
  const int isel = wgrp ? FH0B : FXB;
  int hw[2];
  #pragma unroll
  for (int Gg = 0; Gg < 2; ++Gg)
    hw[Gg] = w4 * 512 + (2 * Gg + (lc >> 3)) * 128 + (lc & 7);
  const int xrow = tid >> 5;
  const int xk0  = 4 * (tid & 31);
  const int xwoff = (xk0 >> 5) * 512 + ((xk0 >> 3) & 3) * 128 + xrow * 8 + (xk0 & 7);
  const float* xg = x + (size_t)(bbase + xrow) * (Tlen * Hd) + xk0;
  const int glo = wgrp ? 2 : 0;
  const int ghi = glo + Tlen;
  {
    int* zb = (int*)Abuf;
    #pragma unroll
    for (int i = 0; i < 8; ++i) zb[2048 + tid + 512 * i] = 0;
    const float4v v0 = *(const float4v*)(xg);
    const float4v v1 = *(const float4v*)(xg + Hd);
    uint2v p0 = {pk2bf(v0[0], v0[1]), pk2bf(v0[2], v0[3])};
    uint2v p1 = {pk2bf(v1[0], v1[1]), pk2bf(v1[2], v1[3])};
    *(short4v*)&Abuf[FXB + xwoff]        = __builtin_bit_cast(short4v, p0);
    *(short4v*)&Abuf[FXB + FBLK + xwoff] = __builtin_bit_cast(short4v, p1);
  }
  __syncthreads();
  const float4v Z4 = {0.f, 0.f, 0.f, 0.f};
  float4v ar[2], az[2], an[2], ah[2];
  float4v hp[2] = {Z4, Z4};
  #pragma unroll
  for (int Gg = 0; Gg < 2; ++Gg) { ar[Gg] = Z4; az[Gg] = Z4; an[Gg] = Z4; ah[Gg] = Z4; }
  #pragma unroll
  for (int s = 0; s < 4; ++s) {
    const short8 a = *(const short8*)&Abuf[isel + s * 512 + lane8];
    #pragma unroll
    for (int Gg = 0; Gg < 2; ++Gg) {
      ar[Gg] = MFMA16(a, fxr[Gg][s], ar[Gg]);
      az[Gg] = MFMA16(a, fxz[Gg][s], az[Gg]);
      an[Gg] = MFMA16(a, fxn[Gg][s], an[Gg]);
    }
  }
  for (int t = 0; t < Tlen + 2; ++t) {
    const int par  = (t & 1) * FBLK;
    const int parx = FBLK - par;
    const int tn = (t + 2 < Tlen) ? (t + 2) : (Tlen - 1);
    const float4v xv = *(const float4v*)(xg + (size_t)tn * Hd);
    const int hrd = hsel + parx;
    #pragma unroll
    for (int s = 0; s < 4; ++s) {
      const short8 a = *(const short8*)&Abuf[hrd + s * 512 + lane8];
      #pragma unroll
      for (int Gg = 0; Gg < 2; ++Gg) {
        ar[Gg] = MFMA16(a, fhr[Gg][s], ar[Gg]);
        az[Gg] = MFMA16(a, fhz[Gg][s], az[Gg]);
        ah[Gg] = MFMA16(a, fhn[Gg][s], ah[Gg]);
      }
    }
    __syncthreads();
    if (t >= glo && t < ghi) {
      const int wr = hsel + par;
      #pragma unroll
      for (int Gg = 0; Gg < 2; ++Gg) {
        #pragma unroll
        for (int i = 0; i < 4; ++i) {
          const float er = fast_exp2(fmaf(ar[Gg][i], nL, kr[Gg]));
          const float rr = fast_rcp(1.0f + er);
          const float ez = fast_exp2(fmaf(az[Gg][i], nL, kz[Gg]));
          const float zz = fast_rcp(1.0f + ez);
          float vv = fmaf(rr, fmaf(ah[Gg][i], n2L, kh[Gg]),
                          fmaf(an[Gg][i], n2L, ki[Gg]));
          vv = fminf(vv, 126.0f);
          const float e2 = fast_exp2(vv);
          const float nn = (1.0f - e2) * fast_rcp(1.0f + e2);
          const float hn = fmaf(zz, hp[Gg][i] - nn, nn);
          hp[Gg][i] = hn;
          Abuf[wr + hw[Gg] + (quad * 4 + i) * 8] = f2bf(hn);
        }
      }
    }
    {
      uint2v pp = {pk2bf(xv[0], xv[1]), pk2bf(xv[2], xv[3])};
      *(short4v*)&Abuf[FXB + par + xwoff] = __builtin_bit_cast(short4v, pp);
    }
    const int ird = isel + parx;
    #pragma unroll
    for (int Gg = 0; Gg < 2; ++Gg) { ar[Gg] = Z4; az[Gg] = Z4; an[Gg] = Z4; ah[Gg] = Z4; }
    #pragma unroll
    for (int s = 0; s < 4; ++s) {
      const short8 a = *(const short8*)&Abuf[ird + s * 512 + lane8];
      #pragma unroll
      for (int Gg = 0; Gg < 2; ++Gg) {
        ar[Gg] = MFMA16(a, fxr[Gg][s], ar[Gg]);
        az[Gg] = MFMA16(a, fxz[Gg][s], az[Gg]);
        an[Gg] = MFMA16(a, fxn[Gg][s], an[Gg]);
      }
    }
    __syncthreads();
  }
  #pragma unroll
  for (int Gg = 0; Gg < 2; ++Gg) {
    const int u = 32 * w4 + 16 * Gg + lc;
    #pragma unroll
    for (int i = 0; i < 4; ++i) {
      const int b = bbase + quad * 4 + i;
      out[wgrp * (Bsz * Hd) + b * Hd + u] = hp[Gg][i];
    }
  }
}

extern "C" void kernel_launch(void* const* d_in, const int* in_sizes, int n_in,
                              void* d_out, int out_size, void* d_ws, size_t ws_size,
                              hipStream_t stream) {
  (void)in_sizes; (void)n_in; (void)out_size;
  const size_t G_bytes = (size_t)4 * Tlen * 8 * 3 * 64 * 4 * 2;  // 201.3 MB
  if (ws_size >= G_bytes) {
    gru_pre<<<128, 512, 0, stream>>>(
        (const float*)d_in[0], (const float*)d_in[1], (short*)d_ws);
    gru_scan<<<4, 512, 0, stream>>>(
        (const float*)d_in[2],
        (const float*)d_in[3], (const float*)d_in[4],
        (const float*)d_in[5], (const float*)d_in[6],
        (const float*)d_in[7], (const float*)d_in[8],
        (const short*)d_ws, (float*)d_out);
  } else {
    gru_scan_fb<<<4, 512, 0, stream>>>(
        (const float*)d_in[0],
        (const float*)d_in[1], (const float*)d_in[2],
        (const float*)d_in[3], (const float*)d_in[4],
        (const float*)d_in[5], (const float*)d_in[6],
        (const float*)d_in[7], (const float*)d_in[8],
        (float*)d_out);
  }
}